// Round 3
// baseline (292.753 us; speedup 1.0000x reference)
//
#include <hip/hip_runtime.h>
#include <math.h>

#define NTH 256

static constexpr float HLP = 0.9189385332046727f; // 0.5*log(2*pi)

// ws layout (float indices):
// [0, 130560)         normalized weights, layers concat (layer l: R=128>>l regions x 64 x 8)
// [130560, 132608)    leafA = exp(-log_sigma)  [256][8]
// [132608, 134656)    leafB = -log_sigma - HLP [256][8]
// [134656, 134664)    srw   = softmax(root_w)  [8]
// [135168, 2232320)   L1 out nPack: uint4[64][8192]   (8 bf16 per uint4)
// [2232320, 2756608)  L1 out M:     float[64][8192]
// [2756608, 3280896)  L3 out nPack: uint4[16][8192]
// [3280896, 3411968)  L3 out M:     float[16][8192]
static constexpr int NW   = 130560;
static constexpr int AOFF = NW;
static constexpr int BOFF = NW + 2048;
static constexpr int ROFF = NW + 4096;
static constexpr int L1N4 = 135168 / 4;     // uint4 index
static constexpr int L1M  = 2232320;
static constexpr int L3N4 = 2756608 / 4;    // uint4 index
static constexpr int L3M  = 3280896;
static constexpr size_t WS_NEED_B = (size_t)3411968 * 4;   // 13,647,872 (proven available in R2)

// weight base (floats) for the layer producing layer-L regions (L=0..7)
// L: 0 -> 0, 1 -> 65536, 2 -> 98304, 3 -> 114688, 4 -> 122880, 5 -> 126976, 6 -> 129024, 7 -> 130048
__device__ __forceinline__ int layer_base(int L) {
  return (256 - (256 >> L)) << 9;
}

// ---------------- prep: normalize weights, leaf constants, root softmax ----------------
__global__ __launch_bounds__(256) void spn_prep(
    const float* __restrict__ ls,
    const float* __restrict__ w0, const float* __restrict__ w1,
    const float* __restrict__ w2, const float* __restrict__ w3,
    const float* __restrict__ w4, const float* __restrict__ w5,
    const float* __restrict__ w6, const float* __restrict__ w7,
    const float* __restrict__ root_w,
    float* __restrict__ ws)
{
  const int job = blockIdx.x * blockDim.x + threadIdx.x;
  if (job < 2040) {
    const float* wl[8] = {w0, w1, w2, w3, w4, w5, w6, w7};
    int j = job, l = 0, base = 0, R = 128;
    while (j >= R * 8) { j -= R * 8; base += R * 512; R >>= 1; ++l; }
    const int r = j >> 3, k = j & 7;
    const float* src = wl[l] + r * 512 + k;
    float v[64];
    float m = -3.0e38f;
    #pragma unroll
    for (int c = 0; c < 64; ++c) { v[c] = src[c * 8]; m = fmaxf(m, v[c]); }
    float ssum = 0.f;
    #pragma unroll
    for (int c = 0; c < 64; ++c) { v[c] = __expf(v[c] - m); ssum += v[c]; }
    const float inv = 1.0f / ssum;
    float* dst = ws + base + r * 512 + k;
    #pragma unroll
    for (int c = 0; c < 64; ++c) dst[c * 8] = v[c] * inv;
  } else if (job < 2040 + 2048) {
    const int i = job - 2040;
    const float l = ls[i];
    ws[AOFF + i] = __expf(-l);
    ws[BOFF + i] = -l - HLP;
  } else if (job == 2040 + 2048) {
    float m = -3.0e38f;
    for (int k = 0; k < 8; ++k) m = fmaxf(m, root_w[k]);
    float e[8]; float ssum = 0.f;
    for (int k = 0; k < 8; ++k) { e[k] = __expf(root_w[k] - m); ssum += e[k]; }
    const float inv = 1.0f / ssum;
    for (int k = 0; k < 8; ++k) ws[ROFF + k] = e[k] * inv;
  }
}

// ---------------- math helpers ----------------
__device__ __forceinline__ void mac64(const float* __restrict__ Wr,
                                      const float* na, const float* nb,
                                      float* s) {
  #pragma unroll
  for (int k = 0; k < 8; ++k) s[k] = 0.f;
  #pragma unroll
  for (int i = 0; i < 8; ++i) {
    const float ai = na[i];
    #pragma unroll
    for (int j = 0; j < 8; ++j) {
      const float e = ai * nb[j];
      const float4 wA = *reinterpret_cast<const float4*>(Wr + (i * 8 + j) * 8);
      const float4 wB = *reinterpret_cast<const float4*>(Wr + (i * 8 + j) * 8 + 4);
      s[0] = fmaf(e, wA.x, s[0]); s[1] = fmaf(e, wA.y, s[1]);
      s[2] = fmaf(e, wA.z, s[2]); s[3] = fmaf(e, wA.w, s[3]);
      s[4] = fmaf(e, wB.x, s[4]); s[5] = fmaf(e, wB.y, s[5]);
      s[6] = fmaf(e, wB.z, s[6]); s[7] = fmaf(e, wB.w, s[7]);
    }
  }
}

__device__ __forceinline__ float max8(const float* s) {
  float m = s[0];
  #pragma unroll
  for (int k = 1; k < 8; ++k) m = fmaxf(m, s[k]);
  return m;
}

__device__ __forceinline__ void combine(const float* __restrict__ W,
                                        const float* na, const float* nb,
                                        float* outn, float* Mio) {
  float s[8];
  mac64(W, na, nb, s);
  const float smax = max8(s);
  const float inv = 1.0f / smax;
  #pragma unroll
  for (int k = 0; k < 8; ++k) outn[k] = s[k] * inv;
  *Mio += __logf(smax);
}

__device__ __forceinline__ void leaf_eval(float xv,
                                          const float* __restrict__ mu8,
                                          const float* __restrict__ A8,
                                          const float* __restrict__ B8,
                                          float* n, float* M) {
  float h[8];
  float m = -3.0e38f;
  #pragma unroll
  for (int k = 0; k < 8; ++k) {
    const float z = (xv - mu8[k]) * A8[k];
    h[k] = fmaf(-0.5f * z, z, B8[k]);
    m = fmaxf(m, h[k]);
  }
  #pragma unroll
  for (int k = 0; k < 8; ++k) n[k] = __expf(h[k] - m);
  *M = m;
}

__device__ __forceinline__ unsigned bf16rne(float f) {
  unsigned u = __float_as_uint(f);
  return (u + 0x7fffu + ((u >> 16) & 1u)) >> 16;
}

__device__ __forceinline__ uint4 pack8(const float* n) {
  uint4 p;
  p.x = bf16rne(n[0]) | (bf16rne(n[1]) << 16);
  p.y = bf16rne(n[2]) | (bf16rne(n[3]) << 16);
  p.z = bf16rne(n[4]) | (bf16rne(n[5]) << 16);
  p.w = bf16rne(n[6]) | (bf16rne(n[7]) << 16);
  return p;
}

__device__ __forceinline__ void unpack8(uint4 p, float* n) {
  n[0] = __uint_as_float(p.x << 16); n[1] = __uint_as_float(p.x & 0xffff0000u);
  n[2] = __uint_as_float(p.y << 16); n[3] = __uint_as_float(p.y & 0xffff0000u);
  n[4] = __uint_as_float(p.z << 16); n[5] = __uint_as_float(p.z & 0xffff0000u);
  n[6] = __uint_as_float(p.w << 16); n[7] = __uint_as_float(p.w & 0xffff0000u);
}

// ---------------- L01: leaves + layer0 (x2) + layer1 -> L1 out ----------------
// grid 2048 blocks x 256; wave = (r1, 64 batches)
__global__ __launch_bounds__(NTH) void spn_L01(
    const float* __restrict__ x,
    const float* __restrict__ mu,
    float* __restrict__ ws)
{
  const int lane = threadIdx.x & 63;
  const int wid  = threadIdx.x >> 6;
  const int r1   = __builtin_amdgcn_readfirstlane(blockIdx.x >> 5);
  const int bc   = blockIdx.x & 31;
  const int b    = ((bc << 2) + wid) * 64 + lane;

  const float4 xv = *reinterpret_cast<const float4*>(x + (size_t)b * 256 + 4 * r1);
  const int f0 = 4 * r1;

  float nA[8], nB[8], Ma, Mb;
  float cA[8], cB[8];

  leaf_eval(xv.x, mu + (f0 + 0) * 8, ws + AOFF + (f0 + 0) * 8, ws + BOFF + (f0 + 0) * 8, nA, &Ma);
  leaf_eval(xv.y, mu + (f0 + 1) * 8, ws + AOFF + (f0 + 1) * 8, ws + BOFF + (f0 + 1) * 8, nB, &Mb);
  float MA = Ma + Mb;
  combine(ws + (2 * r1) * 512, nA, nB, cA, &MA);

  leaf_eval(xv.z, mu + (f0 + 2) * 8, ws + AOFF + (f0 + 2) * 8, ws + BOFF + (f0 + 2) * 8, nA, &Ma);
  leaf_eval(xv.w, mu + (f0 + 3) * 8, ws + AOFF + (f0 + 3) * 8, ws + BOFF + (f0 + 3) * 8, nB, &Mb);
  float MB = Ma + Mb;
  combine(ws + (2 * r1 + 1) * 512, nA, nB, cB, &MB);

  float n[8];
  float M = MA + MB;
  combine(ws + 65536 + r1 * 512, cA, cB, n, &M);

  reinterpret_cast<uint4*>(ws)[L1N4 + r1 * 8192 + b] = pack8(n);
  ws[L1M + r1 * 8192 + b] = M;
}

// ---------------- L23: layer2 (x2) + layer3 -> L3 out ----------------
// grid 512 blocks x 256; wave = (r3, 64 batches)
__global__ __launch_bounds__(NTH) void spn_L23(float* __restrict__ ws)
{
  const int lane = threadIdx.x & 63;
  const int wid  = threadIdx.x >> 6;
  const int r3   = __builtin_amdgcn_readfirstlane(blockIdx.x >> 5);
  const int bc   = blockIdx.x & 31;
  const int b    = ((bc << 2) + wid) * 64 + lane;

  const uint4* n4 = reinterpret_cast<const uint4*>(ws) + L1N4;

  uint4 p0 = n4[(4 * r3 + 0) * 8192 + b];
  uint4 p1 = n4[(4 * r3 + 1) * 8192 + b];
  uint4 p2 = n4[(4 * r3 + 2) * 8192 + b];
  uint4 p3 = n4[(4 * r3 + 3) * 8192 + b];
  float M0 = ws[L1M + (4 * r3 + 0) * 8192 + b];
  float M1 = ws[L1M + (4 * r3 + 1) * 8192 + b];
  float M2 = ws[L1M + (4 * r3 + 2) * 8192 + b];
  float M3 = ws[L1M + (4 * r3 + 3) * 8192 + b];

  float na[8], nb[8], cA[8], cB[8];
  unpack8(p0, na); unpack8(p1, nb);
  float MA = M0 + M1;
  combine(ws + 98304 + (2 * r3) * 512, na, nb, cA, &MA);

  unpack8(p2, na); unpack8(p3, nb);
  float MB = M2 + M3;
  combine(ws + 98304 + (2 * r3 + 1) * 512, na, nb, cB, &MB);

  float n[8];
  float M = MA + MB;
  combine(ws + 114688 + r3 * 512, cA, cB, n, &M);

  reinterpret_cast<uint4*>(ws)[L3N4 + r3 * 8192 + b] = pack8(n);
  ws[L3M + r3 * 8192 + b] = M;
}

// ---------------- tail: layers 4..7 + root, k-parallel (lane = (batch, k)) ----------------
// grid 256 blocks x 256; wave = 8 batches x 8 k-lanes
__global__ __launch_bounds__(NTH) void spn_tail(float* __restrict__ ws,
                                                float* __restrict__ out)
{
  const int lane  = threadIdx.x & 63;
  const int wid   = threadIdx.x >> 6;
  const int myk   = lane & 7;
  const int bsub  = lane >> 3;
  const int gbase = lane & 56;
  const int b     = blockIdx.x * 32 + wid * 8 + bsub;

  const uint4* n4 = reinterpret_cast<const uint4*>(ws) + L3N4;

  // ---- layer 4: 8 regions from 16 stored children
  float n4v[8], M4[8];
  #pragma unroll
  for (int r = 0; r < 8; ++r) {
    uint4 pa = n4[(2 * r + 0) * 8192 + b];
    uint4 pb = n4[(2 * r + 1) * 8192 + b];
    float Ma = ws[L3M + (2 * r + 0) * 8192 + b];
    float Mb = ws[L3M + (2 * r + 1) * 8192 + b];
    float na[8], nb[8];
    unpack8(pa, na); unpack8(pb, nb);
    const float* W = ws + 122880 + r * 512 + myk;
    float s = 0.f;
    #pragma unroll
    for (int c = 0; c < 64; ++c) s = fmaf(na[c >> 3] * nb[c & 7], W[c * 8], s);
    float m = s;
    m = fmaxf(m, __shfl_xor(m, 1)); m = fmaxf(m, __shfl_xor(m, 2)); m = fmaxf(m, __shfl_xor(m, 4));
    n4v[r] = s / m;
    M4[r] = Ma + Mb + __logf(m);
  }

  // ---- layer 5: 4 regions
  float n5v[4], M5[4];
  #pragma unroll
  for (int r = 0; r < 4; ++r) {
    float na[8], nb[8];
    #pragma unroll
    for (int i = 0; i < 8; ++i) {
      na[i] = __shfl(n4v[2 * r], gbase + i, 64);
      nb[i] = __shfl(n4v[2 * r + 1], gbase + i, 64);
    }
    const float* W = ws + 126976 + r * 512 + myk;
    float s = 0.f;
    #pragma unroll
    for (int c = 0; c < 64; ++c) s = fmaf(na[c >> 3] * nb[c & 7], W[c * 8], s);
    float m = s;
    m = fmaxf(m, __shfl_xor(m, 1)); m = fmaxf(m, __shfl_xor(m, 2)); m = fmaxf(m, __shfl_xor(m, 4));
    n5v[r] = s / m;
    M5[r] = M4[2 * r] + M4[2 * r + 1] + __logf(m);
  }

  // ---- layer 6: 2 regions
  float n6v[2], M6[2];
  #pragma unroll
  for (int r = 0; r < 2; ++r) {
    float na[8], nb[8];
    #pragma unroll
    for (int i = 0; i < 8; ++i) {
      na[i] = __shfl(n5v[2 * r], gbase + i, 64);
      nb[i] = __shfl(n5v[2 * r + 1], gbase + i, 64);
    }
    const float* W = ws + 129024 + r * 512 + myk;
    float s = 0.f;
    #pragma unroll
    for (int c = 0; c < 64; ++c) s = fmaf(na[c >> 3] * nb[c & 7], W[c * 8], s);
    float m = s;
    m = fmaxf(m, __shfl_xor(m, 1)); m = fmaxf(m, __shfl_xor(m, 2)); m = fmaxf(m, __shfl_xor(m, 4));
    n6v[r] = s / m;
    M6[r] = M5[2 * r] + M5[2 * r + 1] + __logf(m);
  }

  // ---- layer 7: 1 region
  float na[8], nb[8];
  #pragma unroll
  for (int i = 0; i < 8; ++i) {
    na[i] = __shfl(n6v[0], gbase + i, 64);
    nb[i] = __shfl(n6v[1], gbase + i, 64);
  }
  const float* W = ws + 130048 + myk;
  float s = 0.f;
  #pragma unroll
  for (int c = 0; c < 64; ++c) s = fmaf(na[c >> 3] * nb[c & 7], W[c * 8], s);
  float m = s;
  m = fmaxf(m, __shfl_xor(m, 1)); m = fmaxf(m, __shfl_xor(m, 2)); m = fmaxf(m, __shfl_xor(m, 4));
  const float n7 = s / m;
  const float M7 = M6[0] + M6[1] + __logf(m);

  // ---- root
  float prod = n7 * ws[ROFF + myk];
  prod += __shfl_xor(prod, 1); prod += __shfl_xor(prod, 2); prod += __shfl_xor(prod, 4);
  if (myk == 0) out[b] = M7 + __logf(prod);
}

// ================= fallback (round-1 kernel, tiny ws) =================
#define TB 8
static constexpr int PLA = 128 * 9 + 5;
static constexpr int PLB = 64 * 9 + 5;
static constexpr int NAO = 0;
static constexpr int NBO = TB * PLA;
static constexpr int MAO = NBO + TB * PLB;
static constexpr int MBO = MAO + TB * 128;
static constexpr int SMEM_F = MBO + TB * 64;

__global__ __launch_bounds__(NTH, 2) void spn_main_fb(
    const float* __restrict__ x,
    const float* __restrict__ mu,
    const float* __restrict__ ws,
    float* __restrict__ out)
{
  const float* leafA = ws + AOFF;
  const float* leafB = ws + BOFF;
  const float* srw   = ws + ROFF;

  __shared__ float smem[SMEM_F];

  const int tid = threadIdx.x;
  const int bB = blockIdx.x * TB;

  {
    const float* W0 = ws;
    for (int it = tid; it < TB * 128; it += NTH) {
      const int bb = it & (TB - 1), r = it >> 3;
      float na[8], nb[8], Ma, Mb;
      const int f0 = 2 * r;
      const float xv0 = x[(bB + bb) * 256 + f0];
      const float xv1 = x[(bB + bb) * 256 + f0 + 1];
      leaf_eval(xv0, mu + f0 * 8, leafA + f0 * 8, leafB + f0 * 8, na, &Ma);
      leaf_eval(xv1, mu + f0 * 8 + 8, leafA + f0 * 8 + 8, leafB + f0 * 8 + 8, nb, &Mb);
      float s[8];
      mac64(W0 + r * 512, na, nb, s);
      const float smax = max8(s);
      const float inv = 1.0f / smax;
      const int ob = NAO + bb * PLA + r * 9;
      #pragma unroll
      for (int k = 0; k < 8; ++k) smem[ob + k] = s[k] * inv;
      smem[MAO + bb * 128 + r] = Ma + Mb + __logf(smax);
    }
  }
  __syncthreads();

  int pinO = NAO, poutO = NBO;
  int MinO = MAO, MoutO = MBO;
  int PLIN = PLA, PLOUT = PLB;
  int Rin = 128;
  const float* Wl = ws + 128 * 512;
  for (int l = 1; l < 7; ++l) {
    const int Rout = Rin >> 1;
    for (int it = tid; it < TB * Rout; it += NTH) {
      const int bb = it & (TB - 1), r = it >> 3;
      float na[8], nb[8];
      const int ia = pinO + bb * PLIN + (2 * r) * 9;
      #pragma unroll
      for (int i = 0; i < 8; ++i) { na[i] = smem[ia + i]; nb[i] = smem[ia + 9 + i]; }
      float s[8];
      mac64(Wl + r * 512, na, nb, s);
      const float smax = max8(s);
      const float inv = 1.0f / smax;
      const int ob = poutO + bb * PLOUT + r * 9;
      #pragma unroll
      for (int k = 0; k < 8; ++k) smem[ob + k] = s[k] * inv;
      smem[MoutO + bb * Rout + r] =
          smem[MinO + bb * Rin + 2 * r] + smem[MinO + bb * Rin + 2 * r + 1] + __logf(smax);
    }
    __syncthreads();
    int t;
    t = pinO; pinO = poutO; poutO = t;
    t = MinO; MinO = MoutO; MoutO = t;
    t = PLIN; PLIN = PLOUT; PLOUT = t;
    Rin = Rout;
    Wl += Rout * 512;
  }

  for (int it = tid; it < TB; it += NTH) {
    const int bb = it;
    float na[8], nb[8];
    const int ia = pinO + bb * PLIN;
    #pragma unroll
    for (int i = 0; i < 8; ++i) { na[i] = smem[ia + i]; nb[i] = smem[ia + 9 + i]; }
    float s[8];
    mac64(Wl, na, nb, s);
    float acc = 0.f;
    #pragma unroll
    for (int k = 0; k < 8; ++k) acc = fmaf(s[k], srw[k], acc);
    out[bB + bb] = smem[MinO + bb * 2] + smem[MinO + bb * 2 + 1] + __logf(acc);
  }
}

extern "C" void kernel_launch(void* const* d_in, const int* in_sizes, int n_in,
                              void* d_out, int out_size, void* d_ws, size_t ws_size,
                              hipStream_t stream) {
  const float* x      = (const float*)d_in[0];
  const float* mu     = (const float*)d_in[1];
  const float* ls     = (const float*)d_in[2];
  const float* w0     = (const float*)d_in[3];
  const float* w1     = (const float*)d_in[4];
  const float* w2     = (const float*)d_in[5];
  const float* w3     = (const float*)d_in[6];
  const float* w4     = (const float*)d_in[7];
  const float* w5     = (const float*)d_in[8];
  const float* w6     = (const float*)d_in[9];
  const float* w7     = (const float*)d_in[10];
  const float* root_w = (const float*)d_in[11];
  float* ws  = (float*)d_ws;
  float* out = (float*)d_out;

  spn_prep<<<16, 256, 0, stream>>>(ls, w0, w1, w2, w3, w4, w5, w6, w7, root_w, ws);

  if (ws_size >= WS_NEED_B) {
    spn_L01<<<2048, NTH, 0, stream>>>(x, mu, ws);
    spn_L23<<<512, NTH, 0, stream>>>(ws);
    spn_tail<<<256, NTH, 0, stream>>>(ws, out);
  } else {
    spn_main_fb<<<8192 / TB, NTH, 0, stream>>>(x, mu, ws, out);
  }
}

// Round 4
// 98.029 us; speedup vs baseline: 2.9864x; 2.9864x over previous
//
#include <hip/hip_runtime.h>
#include <math.h>

#define NTH 256

static constexpr float HLP = 0.9189385332046727f; // 0.5*log(2*pi)

// ===================== main-path ws layout (float indices) =====================
// [WBF,  +61440)   bf16-packed normalized weights, layers 0..3, [c][k] pairs.
//                  region dword base: L0 r: r*256 | L1: (128+r)*256 | L2: (192+r)*256 | L3: (224+r)*256
// [WTT,  +3840)    bf16-packed transposed weights layers 4..7, [k][c] pairs, XOR-swizzled chunks.
//                  region order: L4 r=0..7 -> 0..7, L5 -> 8..11, L6 -> 12..13, L7 -> 14
// [AOF2, +2048)    leafA = exp(-log_sigma)   [256][8]
// [BOF2, +2048)    leafB = -log_sigma - HLP  [256][8]
// [ROF2, +8)       srw = softmax(root_w)
// [L1NF, +2097152) L1 n bf16-packed uint4 [64][8192]
// [L1MF, +524288)  L1 M f32 [64][8192]
// [L3NF, +524288)  L3 n bf16-packed uint4 [16][8192]
// [L3MF, +131072)  L3 M f32 [16][8192]
static constexpr int WBF  = 0;
static constexpr int WTT  = 61440;
static constexpr int AOF2 = 65280;
static constexpr int BOF2 = 67328;
static constexpr int ROF2 = 69376;
static constexpr int L1NF = 69632;
static constexpr int L1MF = L1NF + 2097152;   // 2166784
static constexpr int L3NF = L1MF + 524288;    // 2691072
static constexpr int L3MF = L3NF + 524288;    // 3215360
static constexpr size_t WS_NEED_B = (size_t)(L3MF + 131072) * 4;  // 13,385,728

// ===================== helpers =====================
__device__ __forceinline__ unsigned bf16rne(float f) {
  unsigned u = __float_as_uint(f);
  return (u + 0x7fffu + ((u >> 16) & 1u)) >> 16;
}
__device__ __forceinline__ uint4 pack8(const float* n) {
  uint4 p;
  p.x = bf16rne(n[0]) | (bf16rne(n[1]) << 16);
  p.y = bf16rne(n[2]) | (bf16rne(n[3]) << 16);
  p.z = bf16rne(n[4]) | (bf16rne(n[5]) << 16);
  p.w = bf16rne(n[6]) | (bf16rne(n[7]) << 16);
  return p;
}
__device__ __forceinline__ void unpack8(uint4 p, float* n) {
  n[0] = __uint_as_float(p.x << 16); n[1] = __uint_as_float(p.x & 0xffff0000u);
  n[2] = __uint_as_float(p.y << 16); n[3] = __uint_as_float(p.y & 0xffff0000u);
  n[4] = __uint_as_float(p.z << 16); n[5] = __uint_as_float(p.z & 0xffff0000u);
  n[6] = __uint_as_float(p.w << 16); n[7] = __uint_as_float(p.w & 0xffff0000u);
}
__device__ __forceinline__ float max8(const float* s) {
  float m = s[0];
  #pragma unroll
  for (int k = 1; k < 8; ++k) m = fmaxf(m, s[k]);
  return m;
}
__device__ __forceinline__ void leaf_eval(float xv,
                                          const float* mu8,
                                          const float* A8,
                                          const float* B8,
                                          float* n, float* M) {
  float h[8];
  float m = -3.0e38f;
  #pragma unroll
  for (int k = 0; k < 8; ++k) {
    const float z = (xv - mu8[k]) * A8[k];
    h[k] = fmaf(-0.5f * z, z, B8[k]);
    m = fmaxf(m, h[k]);
  }
  #pragma unroll
  for (int k = 0; k < 8; ++k) n[k] = __expf(h[k] - m);
  *M = m;
}

// combineG: s_k = sum_c na[c>>3]*nb[c&7] * W[c][k], from LDS bf16-packed weights.
// WL: 256 dwords in LDS; dword (c*4 + kp) = bf16(w[c][2kp]) | bf16(w[c][2kp+1])<<16
template<int G>
__device__ __forceinline__ void combineG(const uint* WL,
                                         const float (*na)[8], const float (*nb)[8],
                                         float (*outn)[8], float* M) {
  float s[G][8];
  #pragma unroll
  for (int g = 0; g < G; ++g)
    #pragma unroll
    for (int k = 0; k < 8; ++k) s[g][k] = 0.f;
  #pragma unroll
  for (int c = 0; c < 64; ++c) {
    const uint4 w = *reinterpret_cast<const uint4*>(WL + c * 4);
    const float w0 = __uint_as_float(w.x << 16);
    const float w1 = __uint_as_float(w.x & 0xffff0000u);
    const float w2 = __uint_as_float(w.y << 16);
    const float w3 = __uint_as_float(w.y & 0xffff0000u);
    const float w4 = __uint_as_float(w.z << 16);
    const float w5 = __uint_as_float(w.z & 0xffff0000u);
    const float w6 = __uint_as_float(w.w << 16);
    const float w7 = __uint_as_float(w.w & 0xffff0000u);
    #pragma unroll
    for (int g = 0; g < G; ++g) {
      const float e = na[g][c >> 3] * nb[g][c & 7];
      s[g][0] = fmaf(e, w0, s[g][0]); s[g][1] = fmaf(e, w1, s[g][1]);
      s[g][2] = fmaf(e, w2, s[g][2]); s[g][3] = fmaf(e, w3, s[g][3]);
      s[g][4] = fmaf(e, w4, s[g][4]); s[g][5] = fmaf(e, w5, s[g][5]);
      s[g][6] = fmaf(e, w6, s[g][6]); s[g][7] = fmaf(e, w7, s[g][7]);
    }
  }
  #pragma unroll
  for (int g = 0; g < G; ++g) {
    const float smax = max8(s[g]);
    const float inv = 1.0f / smax;
    #pragma unroll
    for (int k = 0; k < 8; ++k) outn[g][k] = s[g][k] * inv;
    M[g] += __logf(smax);
  }
}

// ===================== prep2: softmax -> bf16 packed weights + leaf consts =====================
__global__ __launch_bounds__(256) void spn_prep2(
    const float* __restrict__ ls,
    const float* __restrict__ w0, const float* __restrict__ w1,
    const float* __restrict__ w2, const float* __restrict__ w3,
    const float* __restrict__ w4, const float* __restrict__ w5,
    const float* __restrict__ w6, const float* __restrict__ w7,
    const float* __restrict__ root_w,
    float* __restrict__ ws)
{
  const int job = blockIdx.x * blockDim.x + threadIdx.x;
  uint* wbf = reinterpret_cast<uint*>(ws);
  if (job < 960) {
    // layers 0..3: job -> (layer, region, kpair); softmax columns 2kp, 2kp+1
    const float* wl[4] = {w0, w1, w2, w3};
    int l, r, kp, rbase;
    if (job < 512)      { l = 0; r = job >> 2;          kp = job & 3; rbase = r; }
    else if (job < 768) { l = 1; r = (job - 512) >> 2;  kp = job & 3; rbase = 128 + r; }
    else if (job < 896) { l = 2; r = (job - 768) >> 2;  kp = job & 3; rbase = 192 + r; }
    else                { l = 3; r = (job - 896) >> 2;  kp = job & 3; rbase = 224 + r; }
    const float* s0 = wl[l] + r * 512 + 2 * kp;
    float v0[64], v1[64];
    float m0 = -3.0e38f, m1 = -3.0e38f;
    #pragma unroll
    for (int c = 0; c < 64; ++c) {
      v0[c] = s0[c * 8];     m0 = fmaxf(m0, v0[c]);
      v1[c] = s0[c * 8 + 1]; m1 = fmaxf(m1, v1[c]);
    }
    float t0 = 0.f, t1 = 0.f;
    #pragma unroll
    for (int c = 0; c < 64; ++c) {
      v0[c] = __expf(v0[c] - m0); t0 += v0[c];
      v1[c] = __expf(v1[c] - m1); t1 += v1[c];
    }
    const float i0 = 1.0f / t0, i1 = 1.0f / t1;
    #pragma unroll
    for (int c = 0; c < 64; ++c)
      wbf[WBF + rbase * 256 + c * 4 + kp] = bf16rne(v0[c] * i0) | (bf16rne(v1[c] * i1) << 16);
  } else if (job < 1080) {
    // layers 4..7 transposed [k][c], XOR-swizzled 16B chunks
    const int j = job - 960;
    const int reg = j >> 3, k = j & 7;
    const float* src;
    if (reg < 8)       src = w4 + reg * 512 + k;
    else if (reg < 12) src = w5 + (reg - 8) * 512 + k;
    else if (reg < 14) src = w6 + (reg - 12) * 512 + k;
    else               src = w7 + k;
    float v[64];
    float m = -3.0e38f;
    #pragma unroll
    for (int c = 0; c < 64; ++c) { v[c] = src[c * 8]; m = fmaxf(m, v[c]); }
    float t = 0.f;
    #pragma unroll
    for (int c = 0; c < 64; ++c) { v[c] = __expf(v[c] - m); t += v[c]; }
    const float inv = 1.0f / t;
    #pragma unroll
    for (int cc = 0; cc < 8; ++cc)
      #pragma unroll
      for (int jj = 0; jj < 4; ++jj) {
        const int c = cc * 8 + 2 * jj;
        wbf[WTT + reg * 256 + k * 32 + (((cc ^ k) & 7) << 2) + jj] =
            bf16rne(v[c] * inv) | (bf16rne(v[c + 1] * inv) << 16);
      }
  } else if (job < 1080 + 2048) {
    const int i = job - 1080;
    const float l = ls[i];
    ws[AOF2 + i] = __expf(-l);
    ws[BOF2 + i] = -l - HLP;
  } else if (job == 1080 + 2048) {
    float m = -3.0e38f;
    for (int k = 0; k < 8; ++k) m = fmaxf(m, root_w[k]);
    float e[8]; float t = 0.f;
    for (int k = 0; k < 8; ++k) { e[k] = __expf(root_w[k] - m); t += e[k]; }
    const float inv = 1.0f / t;
    for (int k = 0; k < 8; ++k) ws[ROF2 + k] = e[k] * inv;
  }
}

// ===================== L01: leaves + L0 x2 + L1, G=2 batches/thread =====================
// grid: 64 r1 x 16 chunks = 1024 blocks x 256 thr
__global__ __launch_bounds__(NTH) void spn_L01b(
    const float* __restrict__ x,
    const float* __restrict__ mu,
    float* __restrict__ ws)
{
  __shared__ uint wsh[768];    // W0[2r1], W0[2r1+1], W1[r1]
  __shared__ float lsh[96];    // mu, leafA, leafB for 4 features x 8
  const int tid = threadIdx.x;
  const int r1 = blockIdx.x >> 4;
  const int chunk = blockIdx.x & 15;
  const uint* wbf = reinterpret_cast<const uint*>(ws);

  wsh[tid]       = wbf[(2 * r1) * 256 + tid];
  wsh[256 + tid] = wbf[(2 * r1 + 1) * 256 + tid];
  wsh[512 + tid] = wbf[(128 + r1) * 256 + tid];
  if (tid < 96) {
    const int f8 = r1 * 32;
    float v;
    if (tid < 32)      v = mu[f8 + tid];
    else if (tid < 64) v = ws[AOF2 + f8 + (tid - 32)];
    else               v = ws[BOF2 + f8 + (tid - 64)];
    lsh[tid] = v;
  }
  __syncthreads();

  const int b0 = chunk * 512 + tid;   // g=0: b0, g=1: b0+256
  const float4 xv0 = *reinterpret_cast<const float4*>(x + (size_t)b0 * 256 + 4 * r1);
  const float4 xv1 = *reinterpret_cast<const float4*>(x + (size_t)(b0 + 256) * 256 + 4 * r1);

  float na[2][8], nb[2][8], cA[2][8], cB[2][8];
  float MA[2], MB[2], M[2];
  float Ma, Mb;

  leaf_eval(xv0.x, lsh + 0, lsh + 32, lsh + 64, na[0], &Ma);
  leaf_eval(xv0.y, lsh + 8, lsh + 40, lsh + 72, nb[0], &Mb);
  MA[0] = Ma + Mb;
  leaf_eval(xv1.x, lsh + 0, lsh + 32, lsh + 64, na[1], &Ma);
  leaf_eval(xv1.y, lsh + 8, lsh + 40, lsh + 72, nb[1], &Mb);
  MA[1] = Ma + Mb;
  combineG<2>(wsh, na, nb, cA, MA);

  leaf_eval(xv0.z, lsh + 16, lsh + 48, lsh + 80, na[0], &Ma);
  leaf_eval(xv0.w, lsh + 24, lsh + 56, lsh + 88, nb[0], &Mb);
  MB[0] = Ma + Mb;
  leaf_eval(xv1.z, lsh + 16, lsh + 48, lsh + 80, na[1], &Ma);
  leaf_eval(xv1.w, lsh + 24, lsh + 56, lsh + 88, nb[1], &Mb);
  MB[1] = Ma + Mb;
  combineG<2>(wsh + 256, na, nb, cB, MB);

  M[0] = MA[0] + MB[0];
  M[1] = MA[1] + MB[1];
  combineG<2>(wsh + 512, cA, cB, cA, M);   // output aliases cA (written in epilogue only)

  uint4* outn = reinterpret_cast<uint4*>(ws + L1NF);
  outn[r1 * 8192 + b0]       = pack8(cA[0]);
  outn[r1 * 8192 + b0 + 256] = pack8(cA[1]);
  ws[L1MF + r1 * 8192 + b0]       = M[0];
  ws[L1MF + r1 * 8192 + b0 + 256] = M[1];
}

// ===================== L23: L2 x2 + L3, G=1 =====================
// grid: 16 r3 x 32 chunks = 512 blocks x 256 thr
__global__ __launch_bounds__(NTH) void spn_L23b(float* __restrict__ ws)
{
  __shared__ uint wsh[768];
  const int tid = threadIdx.x;
  const int r3 = blockIdx.x >> 5;
  const int chunk = blockIdx.x & 31;
  const uint* wbf = reinterpret_cast<const uint*>(ws);

  wsh[tid]       = wbf[(192 + 2 * r3) * 256 + tid];
  wsh[256 + tid] = wbf[(192 + 2 * r3 + 1) * 256 + tid];
  wsh[512 + tid] = wbf[(224 + r3) * 256 + tid];
  __syncthreads();

  const int b = chunk * 256 + tid;
  const uint4* n4 = reinterpret_cast<const uint4*>(ws + L1NF);
  const uint4 p0 = n4[(4 * r3 + 0) * 8192 + b];
  const uint4 p1 = n4[(4 * r3 + 1) * 8192 + b];
  const uint4 p2 = n4[(4 * r3 + 2) * 8192 + b];
  const uint4 p3 = n4[(4 * r3 + 3) * 8192 + b];
  const float M0 = ws[L1MF + (4 * r3 + 0) * 8192 + b];
  const float M1 = ws[L1MF + (4 * r3 + 1) * 8192 + b];
  const float M2 = ws[L1MF + (4 * r3 + 2) * 8192 + b];
  const float M3 = ws[L1MF + (4 * r3 + 3) * 8192 + b];

  float na[1][8], nb[1][8], cA[1][8], cB[1][8];
  unpack8(p0, na[0]); unpack8(p1, nb[0]);
  float MA[1] = {M0 + M1};
  combineG<1>(wsh, na, nb, cA, MA);

  unpack8(p2, na[0]); unpack8(p3, nb[0]);
  float MB[1] = {M2 + M3};
  combineG<1>(wsh + 256, na, nb, cB, MB);

  float M[1] = {MA[0] + MB[0]};
  combineG<1>(wsh + 512, cA, cB, cA, M);

  reinterpret_cast<uint4*>(ws + L3NF)[r3 * 8192 + b] = pack8(cA[0]);
  ws[L3MF + r3 * 8192 + b] = M[0];
}

// ===================== tail: layers 4..7 + root, k-parallel =====================
// s_myk = sum_c na[c>>3]*nb[c&7] * Wt[myk][c], Wt in LDS transposed+swizzled
__device__ __forceinline__ float macT(const uint* Wreg, int myk,
                                      const float* na, const float* nb) {
  float s = 0.f;
  #pragma unroll
  for (int cc = 0; cc < 8; ++cc) {
    const uint4 w = *reinterpret_cast<const uint4*>(Wreg + myk * 32 + (((cc ^ myk) & 7) << 2));
    const float w0 = __uint_as_float(w.x << 16);
    const float w1 = __uint_as_float(w.x & 0xffff0000u);
    const float w2 = __uint_as_float(w.y << 16);
    const float w3 = __uint_as_float(w.y & 0xffff0000u);
    const float w4 = __uint_as_float(w.z << 16);
    const float w5 = __uint_as_float(w.z & 0xffff0000u);
    const float w6 = __uint_as_float(w.w << 16);
    const float w7 = __uint_as_float(w.w & 0xffff0000u);
    float inner = nb[0] * w0;
    inner = fmaf(nb[1], w1, inner);
    inner = fmaf(nb[2], w2, inner);
    inner = fmaf(nb[3], w3, inner);
    inner = fmaf(nb[4], w4, inner);
    inner = fmaf(nb[5], w5, inner);
    inner = fmaf(nb[6], w6, inner);
    inner = fmaf(nb[7], w7, inner);
    s = fmaf(na[cc], inner, s);
  }
  return s;
}

__global__ __launch_bounds__(NTH) void spn_tailb(float* __restrict__ ws,
                                                 float* __restrict__ out)
{
  __shared__ uint wsh[3840];
  __shared__ float ssh[8];
  const int tid = threadIdx.x;
  const uint* wbf = reinterpret_cast<const uint*>(ws);
  #pragma unroll
  for (int i = 0; i < 15; ++i) wsh[i * 256 + tid] = wbf[WTT + i * 256 + tid];
  if (tid < 8) ssh[tid] = ws[ROF2 + tid];
  __syncthreads();

  const int lane = tid & 63, wid = tid >> 6;
  const int myk = lane & 7, bsub = lane >> 3, gbase = lane & 56;
  const int b = blockIdx.x * 32 + wid * 8 + bsub;

  const uint4* n4 = reinterpret_cast<const uint4*>(ws + L3NF);

  // ---- layer 4: 8 regions
  float n4v[8], M4[8];
  #pragma unroll
  for (int r = 0; r < 8; ++r) {
    const uint4 pa = n4[(2 * r + 0) * 8192 + b];
    const uint4 pb = n4[(2 * r + 1) * 8192 + b];
    const float Ma = ws[L3MF + (2 * r + 0) * 8192 + b];
    const float Mb = ws[L3MF + (2 * r + 1) * 8192 + b];
    float na[8], nb[8];
    unpack8(pa, na); unpack8(pb, nb);
    float s = macT(wsh + r * 256, myk, na, nb);
    float m = s;
    m = fmaxf(m, __shfl_xor(m, 1)); m = fmaxf(m, __shfl_xor(m, 2)); m = fmaxf(m, __shfl_xor(m, 4));
    n4v[r] = s / m;
    M4[r] = Ma + Mb + __logf(m);
  }

  // ---- layer 5: 4 regions
  float n5v[4], M5[4];
  #pragma unroll
  for (int r = 0; r < 4; ++r) {
    float na[8], nb[8];
    #pragma unroll
    for (int i = 0; i < 8; ++i) {
      na[i] = __shfl(n4v[2 * r], gbase + i, 64);
      nb[i] = __shfl(n4v[2 * r + 1], gbase + i, 64);
    }
    float s = macT(wsh + (8 + r) * 256, myk, na, nb);
    float m = s;
    m = fmaxf(m, __shfl_xor(m, 1)); m = fmaxf(m, __shfl_xor(m, 2)); m = fmaxf(m, __shfl_xor(m, 4));
    n5v[r] = s / m;
    M5[r] = M4[2 * r] + M4[2 * r + 1] + __logf(m);
  }

  // ---- layer 6: 2 regions
  float n6v[2], M6[2];
  #pragma unroll
  for (int r = 0; r < 2; ++r) {
    float na[8], nb[8];
    #pragma unroll
    for (int i = 0; i < 8; ++i) {
      na[i] = __shfl(n5v[2 * r], gbase + i, 64);
      nb[i] = __shfl(n5v[2 * r + 1], gbase + i, 64);
    }
    float s = macT(wsh + (12 + r) * 256, myk, na, nb);
    float m = s;
    m = fmaxf(m, __shfl_xor(m, 1)); m = fmaxf(m, __shfl_xor(m, 2)); m = fmaxf(m, __shfl_xor(m, 4));
    n6v[r] = s / m;
    M6[r] = M5[2 * r] + M5[2 * r + 1] + __logf(m);
  }

  // ---- layer 7 + root
  {
    float na[8], nb[8];
    #pragma unroll
    for (int i = 0; i < 8; ++i) {
      na[i] = __shfl(n6v[0], gbase + i, 64);
      nb[i] = __shfl(n6v[1], gbase + i, 64);
    }
    float s = macT(wsh + 14 * 256, myk, na, nb);
    float m = s;
    m = fmaxf(m, __shfl_xor(m, 1)); m = fmaxf(m, __shfl_xor(m, 2)); m = fmaxf(m, __shfl_xor(m, 4));
    const float n7 = s / m;
    const float M7 = M6[0] + M6[1] + __logf(m);
    float prod = n7 * ssh[myk];
    prod += __shfl_xor(prod, 1); prod += __shfl_xor(prod, 2); prod += __shfl_xor(prod, 4);
    if (myk == 0) out[b] = M7 + __logf(prod);
  }
}

// ===================== fallback path (R1 kernel, proven 145us) =====================
static constexpr int NW   = 130560;
static constexpr int AOFF = NW;
static constexpr int BOFF = NW + 2048;
static constexpr int ROFF = NW + 4096;

__global__ __launch_bounds__(256) void spn_prep(
    const float* __restrict__ ls,
    const float* __restrict__ w0, const float* __restrict__ w1,
    const float* __restrict__ w2, const float* __restrict__ w3,
    const float* __restrict__ w4, const float* __restrict__ w5,
    const float* __restrict__ w6, const float* __restrict__ w7,
    const float* __restrict__ root_w,
    float* __restrict__ ws)
{
  const int job = blockIdx.x * blockDim.x + threadIdx.x;
  if (job < 2040) {
    const float* wl[8] = {w0, w1, w2, w3, w4, w5, w6, w7};
    int j = job, l = 0, base = 0, R = 128;
    while (j >= R * 8) { j -= R * 8; base += R * 512; R >>= 1; ++l; }
    const int r = j >> 3, k = j & 7;
    const float* src = wl[l] + r * 512 + k;
    float v[64];
    float m = -3.0e38f;
    #pragma unroll
    for (int c = 0; c < 64; ++c) { v[c] = src[c * 8]; m = fmaxf(m, v[c]); }
    float ssum = 0.f;
    #pragma unroll
    for (int c = 0; c < 64; ++c) { v[c] = __expf(v[c] - m); ssum += v[c]; }
    const float inv = 1.0f / ssum;
    float* dst = ws + base + r * 512 + k;
    #pragma unroll
    for (int c = 0; c < 64; ++c) dst[c * 8] = v[c] * inv;
  } else if (job < 2040 + 2048) {
    const int i = job - 2040;
    const float l = ls[i];
    ws[AOFF + i] = __expf(-l);
    ws[BOFF + i] = -l - HLP;
  } else if (job == 2040 + 2048) {
    float m = -3.0e38f;
    for (int k = 0; k < 8; ++k) m = fmaxf(m, root_w[k]);
    float e[8]; float ssum = 0.f;
    for (int k = 0; k < 8; ++k) { e[k] = __expf(root_w[k] - m); ssum += e[k]; }
    const float inv = 1.0f / ssum;
    for (int k = 0; k < 8; ++k) ws[ROFF + k] = e[k] * inv;
  }
}

__device__ __forceinline__ void mac64(const float* __restrict__ Wr,
                                      const float* na, const float* nb,
                                      float* s) {
  #pragma unroll
  for (int k = 0; k < 8; ++k) s[k] = 0.f;
  #pragma unroll
  for (int i = 0; i < 8; ++i) {
    const float ai = na[i];
    #pragma unroll
    for (int j = 0; j < 8; ++j) {
      const float e = ai * nb[j];
      const float4 wA = *reinterpret_cast<const float4*>(Wr + (i * 8 + j) * 8);
      const float4 wB = *reinterpret_cast<const float4*>(Wr + (i * 8 + j) * 8 + 4);
      s[0] = fmaf(e, wA.x, s[0]); s[1] = fmaf(e, wA.y, s[1]);
      s[2] = fmaf(e, wA.z, s[2]); s[3] = fmaf(e, wA.w, s[3]);
      s[4] = fmaf(e, wB.x, s[4]); s[5] = fmaf(e, wB.y, s[5]);
      s[6] = fmaf(e, wB.z, s[6]); s[7] = fmaf(e, wB.w, s[7]);
    }
  }
}

#define TB 8
static constexpr int PLA = 128 * 9 + 5;
static constexpr int PLB = 64 * 9 + 5;
static constexpr int NAO = 0;
static constexpr int NBO = TB * PLA;
static constexpr int MAO = NBO + TB * PLB;
static constexpr int MBO = MAO + TB * 128;
static constexpr int SMEM_F = MBO + TB * 64;

__global__ __launch_bounds__(NTH, 2) void spn_main_fb(
    const float* __restrict__ x,
    const float* __restrict__ mu,
    const float* __restrict__ ws,
    float* __restrict__ out)
{
  const float* leafA = ws + AOFF;
  const float* leafB = ws + BOFF;
  const float* srw   = ws + ROFF;

  __shared__ float smem[SMEM_F];

  const int tid = threadIdx.x;
  const int bB = blockIdx.x * TB;

  {
    const float* W0 = ws;
    for (int it = tid; it < TB * 128; it += NTH) {
      const int bb = it & (TB - 1), r = it >> 3;
      float na[8], nb[8], Ma, Mb;
      const int f0 = 2 * r;
      const float xv0 = x[(bB + bb) * 256 + f0];
      const float xv1 = x[(bB + bb) * 256 + f0 + 1];
      leaf_eval(xv0, mu + f0 * 8, leafA + f0 * 8, leafB + f0 * 8, na, &Ma);
      leaf_eval(xv1, mu + f0 * 8 + 8, leafA + f0 * 8 + 8, leafB + f0 * 8 + 8, nb, &Mb);
      float s[8];
      mac64(W0 + r * 512, na, nb, s);
      const float smax = max8(s);
      const float inv = 1.0f / smax;
      const int ob = NAO + bb * PLA + r * 9;
      #pragma unroll
      for (int k = 0; k < 8; ++k) smem[ob + k] = s[k] * inv;
      smem[MAO + bb * 128 + r] = Ma + Mb + __logf(smax);
    }
  }
  __syncthreads();

  int pinO = NAO, poutO = NBO;
  int MinO = MAO, MoutO = MBO;
  int PLIN = PLA, PLOUT = PLB;
  int Rin = 128;
  const float* Wl = ws + 128 * 512;
  for (int l = 1; l < 7; ++l) {
    const int Rout = Rin >> 1;
    for (int it = tid; it < TB * Rout; it += NTH) {
      const int bb = it & (TB - 1), r = it >> 3;
      float na[8], nb[8];
      const int ia = pinO + bb * PLIN + (2 * r) * 9;
      #pragma unroll
      for (int i = 0; i < 8; ++i) { na[i] = smem[ia + i]; nb[i] = smem[ia + 9 + i]; }
      float s[8];
      mac64(Wl + r * 512, na, nb, s);
      const float smax = max8(s);
      const float inv = 1.0f / smax;
      const int ob = poutO + bb * PLOUT + r * 9;
      #pragma unroll
      for (int k = 0; k < 8; ++k) smem[ob + k] = s[k] * inv;
      smem[MoutO + bb * Rout + r] =
          smem[MinO + bb * Rin + 2 * r] + smem[MinO + bb * Rin + 2 * r + 1] + __logf(smax);
    }
    __syncthreads();
    int t;
    t = pinO; pinO = poutO; poutO = t;
    t = MinO; MinO = MoutO; MoutO = t;
    t = PLIN; PLIN = PLOUT; PLOUT = t;
    Rin = Rout;
    Wl += Rout * 512;
  }

  for (int it = tid; it < TB; it += NTH) {
    const int bb = it;
    float na[8], nb[8];
    const int ia = pinO + bb * PLIN;
    #pragma unroll
    for (int i = 0; i < 8; ++i) { na[i] = smem[ia + i]; nb[i] = smem[ia + 9 + i]; }
    float s[8];
    mac64(Wl, na, nb, s);
    float acc = 0.f;
    #pragma unroll
    for (int k = 0; k < 8; ++k) acc = fmaf(s[k], srw[k], acc);
    out[bB + bb] = smem[MinO + bb * 2] + smem[MinO + bb * 2 + 1] + __logf(acc);
  }
}

extern "C" void kernel_launch(void* const* d_in, const int* in_sizes, int n_in,
                              void* d_out, int out_size, void* d_ws, size_t ws_size,
                              hipStream_t stream) {
  (void)in_sizes; (void)n_in; (void)out_size;
  const float* x      = (const float*)d_in[0];
  const float* mu     = (const float*)d_in[1];
  const float* ls     = (const float*)d_in[2];
  const float* w0     = (const float*)d_in[3];
  const float* w1     = (const float*)d_in[4];
  const float* w2     = (const float*)d_in[5];
  const float* w3     = (const float*)d_in[6];
  const float* w4     = (const float*)d_in[7];
  const float* w5     = (const float*)d_in[8];
  const float* w6     = (const float*)d_in[9];
  const float* w7     = (const float*)d_in[10];
  const float* root_w = (const float*)d_in[11];
  float* ws  = (float*)d_ws;
  float* out = (float*)d_out;

  if (ws_size >= WS_NEED_B) {
    spn_prep2<<<13, 256, 0, stream>>>(ls, w0, w1, w2, w3, w4, w5, w6, w7, root_w, ws);
    spn_L01b<<<1024, NTH, 0, stream>>>(x, mu, ws);
    spn_L23b<<<512, NTH, 0, stream>>>(ws);
    spn_tailb<<<256, NTH, 0, stream>>>(ws, out);
  } else {
    spn_prep<<<16, 256, 0, stream>>>(ls, w0, w1, w2, w3, w4, w5, w6, w7, root_w, ws);
    spn_main_fb<<<8192 / TB, NTH, 0, stream>>>(x, mu, ws, out);
  }
}